// Round 13
// baseline (1162.670 us; speedup 1.0000x reference)
//
#include <hip/hip_runtime.h>

#define BB 32
#define HH 256
#define WW 256
#define CC 4
#define KH 5
#define KW 5
#define FF 8
#define HO (HH - KH + 1)   // 252
#define WO (WW - KW + 1)   // 252
#define PX 2               // output pixels per thread along x; WO % PX == 0
#define NXT (WO / PX)      // 126
#define NCOL (PX + KW - 1) // 6 input columns per thread
#define NTAP (KH * KW)     // 25

typedef _Float16 h2      __attribute__((ext_vector_type(2)));
typedef __fp16   fp16x2  __attribute__((ext_vector_type(2)));
typedef unsigned int u32x4 __attribute__((ext_vector_type(4)));

static __device__ __forceinline__ h2 pkrtz(float a, float b) {
    fp16x2 r = __builtin_amdgcn_cvt_pkrtz(a, b);
    return __builtin_bit_cast(h2, r);
}
static __device__ __forceinline__ h2 ash2(unsigned int u) {
    return __builtin_bit_cast(h2, u);
}

// R13 = R6 (best: 61.4 us) + __launch_bounds__(256, 4) [the R12 experiment],
// with R12's LDS indexing bug fixed (&lw[tap*4], not &lw[tap] — R12 read
// tap*4 dwords instead of tap*16 and failed validation).
// Rationale: R6's ~80-dword live set couldn't fit the default 64-VGPR
// allocation, serializing each tap (ds_read x4 -> lgkmcnt(0) -> 64 VALU,
// ~120cy unhidden LDS latency -> 47.6% VALUBusy). 128-VGPR budget at the
// same 16-waves/CU bucket lets the compiler's OWN scheduler prefetch ahead.
// No hand pipeline, no fences (0-for-6 record on those).
// LDS dword i = tap*16 + f*2 + pair : pk(k[tap, 2*pair, f], k[tap, 2*pair+1, f])
__global__ __launch_bounds__(256, 4) void erosion2d_f16(
    const float* __restrict__ x,
    const float* __restrict__ k,
    float* __restrict__ out)
{
    __shared__ u32x4 lw[NTAP * 4];   // 400 dwords = 1.6 KB, b128-aligned
    unsigned int* lws = reinterpret_cast<unsigned int*>(lw);

    for (int i = threadIdx.x; i < NTAP * 16; i += 256) {
        int t = i >> 4;          // tap
        int rr = i & 15;
        int f = rr >> 1;
        int p = rr & 1;          // channel pair
        float a = k[(t * CC + 2 * p + 0) * FF + f];
        float b = k[(t * CC + 2 * p + 1) * FF + f];
        lws[i] = __builtin_bit_cast(unsigned int, pkrtz(a, b));
    }
    __syncthreads();

    // Grid is exact: 3969 * 256 == 32 * 252 * 126 — no bounds check needed.
    int tid = blockIdx.x * blockDim.x + threadIdx.x;

    int b   = tid / (HO * NXT);
    int rem = tid - b * (HO * NXT);
    int y   = rem / NXT;
    int xt  = rem - y * NXT;
    const int x0 = xt * PX;

    const float* xb = x + (((size_t)b * HH + y) * WW + x0) * CC;

    h2 acc[PX][FF];
    float4 raw[NCOL];
    h2 cur[NCOL][2];

    // Row 0 loads in flight.
#pragma unroll
    for (int j = 0; j < NCOL; ++j)
        raw[j] = *reinterpret_cast<const float4*>(xb + j * CC);

#pragma unroll
    for (int r = 0; r < KH; ++r) {
        // Convert the row whose loads we just waited on.
#pragma unroll
        for (int j = 0; j < NCOL; ++j) {
            cur[j][0] = pkrtz(raw[j].x, raw[j].y);
            cur[j][1] = pkrtz(raw[j].z, raw[j].w);
        }
        // Issue next row's loads; consumed only after this row's 320 VALU ops.
        if (r + 1 < KH) {
#pragma unroll
            for (int j = 0; j < NCOL; ++j)
                raw[j] = *reinterpret_cast<const float4*>(xb + ((r + 1) * WW + j) * CC);
        }
#pragma unroll
        for (int dx = 0; dx < KW; ++dx) {
            const int tap = r * KW + dx;
            const u32x4* q = &lw[tap * 4];            // FIX: tap*4 u32x4 = dword tap*16
            const u32x4 q0 = q[0], q1 = q[1], q2 = q[2], q3 = q[3];
            h2 w01[FF], w23[FF];
            w01[0] = ash2(q0[0]); w23[0] = ash2(q0[1]);
            w01[1] = ash2(q0[2]); w23[1] = ash2(q0[3]);
            w01[2] = ash2(q1[0]); w23[2] = ash2(q1[1]);
            w01[3] = ash2(q1[2]); w23[3] = ash2(q1[3]);
            w01[4] = ash2(q2[0]); w23[4] = ash2(q2[1]);
            w01[5] = ash2(q2[2]); w23[5] = ash2(q2[3]);
            w01[6] = ash2(q3[0]); w23[6] = ash2(q3[1]);
            w01[7] = ash2(q3[2]); w23[7] = ash2(q3[3]);
#pragma unroll
            for (int p = 0; p < PX; ++p) {
                const h2 c01 = cur[dx + p][0];
                const h2 c23 = cur[dx + p][1];
#pragma unroll
                for (int f = 0; f < FF; ++f) {
                    h2 d01 = c01 - w01[f];
                    h2 d23 = c23 - w23[f];
                    h2 m   = __builtin_elementwise_min(d01, d23);
                    if (tap == 0)
                        acc[p][f] = m;                 // init from first tap
                    else
                        acc[p][f] = __builtin_elementwise_min(acc[p][f], m);
                }
            }
        }
    }

    // Epilogue: horizontal min over the channel pair, f16->f32, 64 B/thread.
#pragma unroll
    for (int p = 0; p < PX; ++p) {
        float rr[FF];
#pragma unroll
        for (int f = 0; f < FF; ++f) {
            _Float16 m = __builtin_elementwise_min(acc[p][f][0], acc[p][f][1]);
            rr[f] = (float)m;
        }
        float* op = out + ((size_t)tid * PX + p) * FF;
        *reinterpret_cast<float4*>(op)     = make_float4(rr[0], rr[1], rr[2], rr[3]);
        *reinterpret_cast<float4*>(op + 4) = make_float4(rr[4], rr[5], rr[6], rr[7]);
    }
}

extern "C" void kernel_launch(void* const* d_in, const int* in_sizes, int n_in,
                              void* d_out, int out_size, void* d_ws, size_t ws_size,
                              hipStream_t stream) {
    const float* x = (const float*)d_in[0];
    const float* k = (const float*)d_in[1];
    float* out = (float*)d_out;

    const int total = BB * HO * NXT;                 // 1,016,064 threads
    const int block = 256;
    const int grid  = total / block;                 // 3969 blocks, exact
    erosion2d_f16<<<grid, block, 0, stream>>>(x, k, out);
}

// Round 14
// 68.690 us; speedup vs baseline: 16.9262x; 16.9262x over previous
//
#include <hip/hip_runtime.h>

#define BB 32
#define HH 256
#define WW 256
#define CC 4
#define KH 5
#define KW 5
#define FF 8
#define HO (HH - KH + 1)   // 252
#define WO (WW - KW + 1)   // 252
#define TH 4               // output rows per block
#define TW 126             // output cols per block (2 tiles cover 252)
#define NYT (HO / TH)      // 63
#define IR (TH + KH - 1)   // 8 input rows staged
#define IC (TW + KW - 1)   // 130 input cols staged
#define ICP 132            // padded LDS row stride (u32)
#define NTAP (KH * KW)     // 25

typedef _Float16 h2      __attribute__((ext_vector_type(2)));
typedef __fp16   fp16x2  __attribute__((ext_vector_type(2)));
typedef unsigned int u32x2 __attribute__((ext_vector_type(2)));

static __device__ __forceinline__ h2 pkrtz(float a, float b) {
    fp16x2 r = __builtin_amdgcn_cvt_pkrtz(a, b);
    return __builtin_bit_cast(h2, r);
}
static __device__ __forceinline__ h2 ash2(unsigned int u) {
    return __builtin_bit_cast(h2, u);
}

// --- Kernel A: pre-pack weights into f16 channel pairs in d_ws (R3 layout).
// dword i = tap*16 + f*2 + pair : pk(k[tap, 2*pair, f], k[tap, 2*pair+1, f])
__global__ void pack_kernel(const float* __restrict__ k, unsigned int* __restrict__ kp)
{
    int i = blockIdx.x * blockDim.x + threadIdx.x;
    if (i >= NTAP * 16) return;
    int t = i >> 4;
    int r = i & 15;
    int f = r >> 1;
    int p = r & 1;
    float a = k[(t * CC + 2 * p + 0) * FF + f];
    float b = k[(t * CC + 2 * p + 1) * FF + f];
    kp[i] = __builtin_bit_cast(unsigned int, pkrtz(a, b));
}

// --- Kernel B: block-tiled erosion. Input staged ONCE per block in LDS as
// f16 channel-pair planes (cvt 30 -> ~4 per output; inner loop reads are
// 2-way-conflict-free ds_read_b64 = free per m136). Weights via SMEM
// (s_load_dwordx16 per tap, SGPR operands of v_pk_*_f16) — zero LDS-pipe
// cost (R6 burned ~31us of LDS pipe re-reading weights), zero VGPR cost.
// Lean live set (~45 VGPR) -> 5+ waves/SIMD. No hand pipeline, no fences,
// no launch-bounds caps (0-for-5 on allocator coercion).
__global__ __launch_bounds__(256) void erosion2d_tile(
    const float* __restrict__ x,
    const h2* __restrict__ k2,        // d_ws, layout above
    float* __restrict__ out)
{
    __shared__ unsigned int pl[2][IR][ICP];   // two channel-pair planes, 8.4 KB

    const int g  = blockIdx.x;                // grid = BB * NYT * 2 = 4032
    const int bx = g & 1;
    const int t2 = g >> 1;
    const int gy = t2 % NYT;
    const int b  = t2 / NYT;
    const int x0 = bx * TW;
    const int y0 = gy * TH;

    const int tid = threadIdx.x;

    // ---- stage 8x130 input pixels -> f16 planes (coalesced float4 loads,
    // stride-1 u32 LDS writes: conflict-free) ----
    const float* xb = x + (((size_t)b * HH + y0) * WW + x0) * CC;
    for (int i = tid; i < IR * IC; i += 256) {
        int r = i / IC;
        int c = i - r * IC;
        float4 px = *reinterpret_cast<const float4*>(xb + (r * WW + c) * CC);
        pl[0][r][c] = __builtin_bit_cast(unsigned int, pkrtz(px.x, px.y));
        pl[1][r][c] = __builtin_bit_cast(unsigned int, pkrtz(px.z, px.w));
    }
    __syncthreads();

    // ---- compute: thread (ty, tx) -> output row y0+ty, cols x0+2tx(+1) ----
    const int tx = tid & 63;      // 0..63; tx==63 idle (63*2=126 cols covered)
    const int ty = tid >> 6;      // 0..3
    if (tx < 63) {
        h2 acc[2][FF];
#pragma unroll
        for (int r = 0; r < KH; ++r) {
            // Window: input row ty+r, cols 2tx..2tx+5, both planes.
            // 6x ds_read_b64; lanes t and t+16 alias a bank = 2-way = free.
            const u32x2* w0p = reinterpret_cast<const u32x2*>(&pl[0][ty + r][2 * tx]);
            const u32x2* w1p = reinterpret_cast<const u32x2*>(&pl[1][ty + r][2 * tx]);
            const u32x2 a0 = w0p[0], a1 = w0p[1], a2 = w0p[2];
            const u32x2 b0 = w1p[0], b1 = w1p[1], b2 = w1p[2];
            const h2 c01[6] = { ash2(a0[0]), ash2(a0[1]), ash2(a1[0]),
                                ash2(a1[1]), ash2(a2[0]), ash2(a2[1]) };
            const h2 c23[6] = { ash2(b0[0]), ash2(b0[1]), ash2(b1[0]),
                                ash2(b1[1]), ash2(b2[0]), ash2(b2[1]) };
#pragma unroll
            for (int dx = 0; dx < KW; ++dx) {
                // Wave-uniform weight block: one s_load_dwordx16 feeding
                // 64 packed VALU ops below (SGPR operands, no LDS).
                const h2* kw = k2 + (r * KW + dx) * 16;
#pragma unroll
                for (int p = 0; p < 2; ++p) {
                    const h2 u01 = c01[dx + p];
                    const h2 u23 = c23[dx + p];
#pragma unroll
                    for (int f = 0; f < FF; ++f) {
                        h2 d01 = u01 - kw[f * 2 + 0];
                        h2 d23 = u23 - kw[f * 2 + 1];
                        h2 m   = __builtin_elementwise_min(d01, d23);
                        if (r == 0 && dx == 0)
                            acc[p][f] = m;             // first tap initializes
                        else
                            acc[p][f] = __builtin_elementwise_min(acc[p][f], m);
                    }
                }
            }
        }

        // ---- epilogue: hmin over channel pair, f16->f32, 64 B/thread ----
        const int oy = y0 + ty;
        const int ox = x0 + 2 * tx;
#pragma unroll
        for (int p = 0; p < 2; ++p) {
            float rr[FF];
#pragma unroll
            for (int f = 0; f < FF; ++f) {
                _Float16 m = __builtin_elementwise_min(acc[p][f][0], acc[p][f][1]);
                rr[f] = (float)m;
            }
            float* op = out + (((size_t)b * HO + oy) * WO + (ox + p)) * FF;
            *reinterpret_cast<float4*>(op)     = make_float4(rr[0], rr[1], rr[2], rr[3]);
            *reinterpret_cast<float4*>(op + 4) = make_float4(rr[4], rr[5], rr[6], rr[7]);
        }
    }
}

extern "C" void kernel_launch(void* const* d_in, const int* in_sizes, int n_in,
                              void* d_out, int out_size, void* d_ws, size_t ws_size,
                              hipStream_t stream) {
    const float* x = (const float*)d_in[0];
    const float* k = (const float*)d_in[1];
    float* out = (float*)d_out;

    pack_kernel<<<2, 256, 0, stream>>>(k, (unsigned int*)d_ws);

    const int grid = BB * NYT * 2;                   // 4032 blocks
    erosion2d_tile<<<grid, 256, 0, stream>>>(x, (const h2*)d_ws, out);
}